// Round 18
// baseline (476.071 us; speedup 1.0000x reference)
//
#include <hip/hip_runtime.h>
#include <hip/hip_bf16.h>

#define Nn 200000
#define Cc 1000
#define Dd 256
#define PAD 16        // counter padding (one per 64B line)
#define NCH8 3125     // Nn / 64 chunks, one per block
#define CAP 512       // per-cluster order capacity (mean 200, sigma 14 -> +22 sigma)

typedef float f32x16 __attribute__((ext_vector_type(16)));
typedef short bf16x8 __attribute__((ext_vector_type(8)));
typedef _Float16 f16x2 __attribute__((ext_vector_type(2)));

#define LOG2E  1.4426950408889634f
#define LOG2E2 2.8853900817779268f

__device__ __forceinline__ unsigned int f2bf(float x){
    union { float f; unsigned int u; } c; c.f = x;
    unsigned int u = c.u;
    u += 0x7fffu + ((u >> 16) & 1u);   // round-to-nearest-even
    return u >> 16;
}
__device__ __forceinline__ float bf2f(unsigned short b){
    union { unsigned int u; float f; } c; c.u = ((unsigned int)b) << 16;
    return c.f;
}
__device__ __forceinline__ float rcp_(float x){ return __builtin_amdgcn_rcpf(x); }
// packed fp32->bf16 (RNE), 2 values per instruction; pure-VALU asm (no mem-ordering hazard)
__device__ __forceinline__ unsigned int cvtpk_bf16(float lo, float hi){
    unsigned int r;
    asm("v_cvt_pk_bf16_f32 %0, %1, %2" : "=v"(r) : "v"(lo), "v"(hi));
    return r;
}

// ---------------- prep: W fragment tables (MFMA 32x32x16 operand order) + zero cnt ----------------
__global__ void k_prep(const float* __restrict__ Wk, const float* __restrict__ H1w,
                       unsigned short* __restrict__ wfragK, unsigned short* __restrict__ wfragH,
                       int* __restrict__ cnt){
    int t = blockIdx.x*256 + threadIdx.x;       // 64 x 256 = 16384
    if (t < Cc*PAD) cnt[t] = 0;
    int arr = t >> 13;
    int s   = t & 8191;
    int ct  = s >> 10;
    int kk  = (s >> 6) & 15;
    int l   = s & 63;
    int col = ct*32 + (l & 31);
    int k0  = kk*16 + (l >> 5)*8;
    const float* W = arr ? H1w : Wk;
    unsigned short* dst = (arr ? wfragH : wfragK) + (size_t)s*8;
    #pragma unroll
    for (int e = 0; e < 8; ++e) dst[e] = (unsigned short)f2bf(W[(size_t)(k0+e)*Dd + col]);
}

// ---------------- per-cluster precompute: 1 cluster/block, 512 thr, 2-way k-split ----------------
__global__ __launch_bounds__(512)
void k_cluster_prep(const float* __restrict__ g, const float* __restrict__ Wq,
                    const float* __restrict__ b_attn,
                    const float* __restrict__ Ws, const float* __restrict__ bs,
                    const float* __restrict__ G1w, const float* __restrict__ G1b,
                    const float* __restrict__ H1b,
                    float* __restrict__ qb, unsigned int* __restrict__ ctht){
    int c = blockIdx.x, t = threadIdx.x;
    int d = t & 255, half = t >> 8;
    __shared__ float gL[Dd], htL[Dd];
    __shared__ float redA[2][Dd], redS[2][Dd];
    if (half == 0) gL[d] = g[(size_t)c*Dd + d];
    __syncthreads();
    int k0 = half*128;
    float aq = 0.f, as = 0.f;
    #pragma unroll 4
    for (int k2 = 0; k2 < 128; ++k2){
        int k = k0 + k2;
        float gv = gL[k];
        aq = fmaf(gv, Wq[k*Dd + d], aq);
        as = fmaf(gv, Ws[k*Dd + d], as);
    }
    redA[half][d] = aq;
    redS[half][d] = as;
    __syncthreads();
    if (half == 0){
        qb[(size_t)c*Dd + d] = redA[0][d] + redA[1][d] + b_attn[d];
        htL[d] = tanhf(redS[0][d] + redS[1][d] + bs[d]);
    }
    __syncthreads();
    float ac = 0.f;
    #pragma unroll 4
    for (int k2 = 0; k2 < 128; ++k2){
        int k = k0 + k2;
        ac = fmaf(htL[k], G1w[k*Dd + d], ac);
    }
    redA[half][d] = ac;
    __syncthreads();
    if (half == 0){
        float acv = redA[0][d] + redA[1][d] + H1b[d] + G1b[d];
        ctht[(size_t)c*Dd + d] = (f2bf(acv) << 16) | f2bf(htL[d]);
    }
}

// ---------------- capacity-bucket scatter (no scan needed; order within cluster irrelevant) ----------------
__global__ void k_scatter(const int* __restrict__ seg, int* __restrict__ cnt, int* __restrict__ order){
    int i = blockIdx.x*256 + threadIdx.x;
    if (i < Nn){
        int c = seg[i];
        int p = atomicAdd(&cnt[c*PAD], 1);
        if (p < CAP) order[c*CAP + p] = i;
    }
}

// ================= fused GEMM v9: 8 waves; each wave owns a (score, merge) col-tile PAIR =================
// vs R17: hF0/hF1 LDS reads feed 4 MFMAs instead of 2 -> k-loop ds_read_b128 per block 512->256
// (the largest LDS-pipe consumer). Staging uses v_cvt_pk_bf16_f32 (1 instr / 2 values).
// Wave w: score frag slice ct=w (Wk cols w*32..), merge slice ct=w+8 (H1w cols w*32..).
__global__ __launch_bounds__(512, 4)
void k_gemm9(const float* __restrict__ h, const unsigned short* __restrict__ wfrag,
             const int* __restrict__ seg, const float* __restrict__ qb,
             const float* __restrict__ w_score, const float* __restrict__ b_score,
             const unsigned int* __restrict__ ctht,
             float* __restrict__ e, float* __restrict__ out){
    __shared__ __align__(16) char Al[32768];    // 64 nodes x 512B bf16, XOR-swizzled
    __shared__ float sPart[64][8];
    __shared__ int segL[64];

    int tid = threadIdx.x;
    int w = tid >> 6, l = tid & 63;             // w = 0..7
    int lCol = l & 31, hiK = l >> 5;
    int rowBase = blockIdx.x * 64;

    // ---- stage A tile: 8 float4 loads/thread, cvt_pk bf16 pack, swizzled LDS writes ----
    {
        const float4* hv = reinterpret_cast<const float4*>(h + (size_t)rowBase * Dd);
        float4 v[8];
        #pragma unroll
        for (int j = 0; j < 8; ++j) v[j] = hv[j*512 + tid];
        if (tid < 64) segL[tid] = seg[rowBase + tid];
        #pragma unroll
        for (int j = 0; j < 8; ++j){
            int f = j*512 + tid;
            int row = f >> 6;
            uint2 pk;
            pk.x = cvtpk_bf16(v[j].x, v[j].y);
            pk.y = cvtpk_bf16(v[j].z, v[j].w);
            int byte = (row*512 + (f & 63)*8) ^ ((row & 15) << 4);
            *reinterpret_cast<uint2*>(Al + byte) = pk;
        }
    }
    __syncthreads();   // A ready

    int hOff = lCol*512;
    int swzK = (lCol & 15) << 4;
    const char* wbS = reinterpret_cast<const char*>(wfrag) + (size_t)w*16384     + l*16;
    const char* wbM = reinterpret_cast<const char*>(wfrag) + (size_t)(w+8)*16384 + l*16;

    f32x16 aS0, aS1, aM0, aM1;
    #pragma unroll
    for (int i = 0; i < 16; ++i){ aS0[i] = 0.f; aS1[i] = 0.f; aM0[i] = 0.f; aM1[i] = 0.f; }
    #pragma unroll
    for (int kk = 0; kk < 16; ++kk){
        bf16x8 wFS = *reinterpret_cast<const bf16x8*>(wbS + (size_t)kk*1024);
        bf16x8 wFM = *reinterpret_cast<const bf16x8*>(wbM + (size_t)kk*1024);
        int hb = (hOff + kk*32 + hiK*16) ^ swzK;
        bf16x8 hF0 = *reinterpret_cast<const bf16x8*>(Al + hb);
        bf16x8 hF1 = *reinterpret_cast<const bf16x8*>(Al + 16384 + hb);
        aS0 = __builtin_amdgcn_mfma_f32_32x32x16_bf16(hF0, wFS, aS0, 0, 0, 0);
        aS1 = __builtin_amdgcn_mfma_f32_32x32x16_bf16(hF1, wFS, aS1, 0, 0, 0);
        aM0 = __builtin_amdgcn_mfma_f32_32x32x16_bf16(hF0, wFM, aM0, 0, 0, 0);
        aM1 = __builtin_amdgcn_mfma_f32_32x32x16_bf16(hF1, wFM, aM1, 0, 0, 0);
    }

    // ---- score epilogue: packed-f16 pairwise reduction (R17-proven) ----
    {
        float wsc = w_score[w*32 + lCol];
        #pragma unroll
        for (int nt = 0; nt < 2; ++nt){
            const f32x16& A = nt ? aS1 : aS0;
            #pragma unroll
            for (int p = 0; p < 8; ++p){
                int i0 = 2*p, i1 = 2*p + 1;
                int n0 = nt*32 + (i0&3) + 8*(i0>>2) + 4*hiK;
                int n1 = nt*32 + (i1&3) + 8*(i1>>2) + 4*hiK;
                float q0 = qb[(size_t)segL[n0]*Dd + w*32 + lCol];
                float q1 = qb[(size_t)segL[n1]*Dd + w*32 + lCol];
                float t0 = exp2f(LOG2E2*(A[i0] + q0));
                float t1 = exp2f(LOG2E2*(A[i1] + q1));
                float v0 = (t0 - 1.f)*rcp_(t0 + 1.f)*wsc;
                float v1 = (t1 - 1.f)*rcp_(t1 + 1.f)*wsc;
                f16x2 pk; pk.x = (_Float16)v0; pk.y = (_Float16)v1;
                #pragma unroll
                for (int off = 1; off <= 16; off <<= 1){
                    union { f16x2 f; int i; } cv, co;
                    cv.f = pk;
                    co.i = __shfl_xor(cv.i, off);
                    pk = pk + co.f;              // v_pk_add_f16: both rows per op
                }
                if (lCol == 0){
                    sPart[n0][w] = (float)pk.x;
                    sPart[n1][w] = (float)pk.y;
                }
            }
        }
    }

    // ---- merge epilogue: z = sigmoid(y + ct); out = h + z*(ht - h) ----
    {
        int cb = w*32 + lCol;
        #pragma unroll
        for (int nt = 0; nt < 2; ++nt){
            const f32x16& A = nt ? aM1 : aM0;
            #pragma unroll
            for (int i = 0; i < 16; ++i){
                int node = nt*32 + (i&3) + 8*(i>>2) + 4*hiK;
                unsigned int v = ctht[(size_t)segL[node]*Dd + cb];
                float c4 = bf2f((unsigned short)(v >> 16));
                float t4 = bf2f((unsigned short)(v & 0xffff));
                unsigned short hb = *reinterpret_cast<const unsigned short*>(
                    Al + ((node*512 + cb*2) ^ ((node & 15) << 4)));
                float hval = bf2f(hb);
                float z = rcp_(1.f + exp2f(-LOG2E*(A[i] + c4)));
                out[(size_t)(rowBase + node)*Dd + cb] = fmaf(z, t4 - hval, hval);
            }
        }
    }

    __syncthreads();   // sPart complete
    if (tid < 64){
        float s = sPart[tid][0] + sPart[tid][1] + sPart[tid][2] + sPart[tid][3]
                + sPart[tid][4] + sPart[tid][5] + sPart[tid][6] + sPart[tid][7] + b_score[0];
        e[rowBase + tid] = exp2f(LOG2E * s);   // unshifted exp: |s| small, ratio == ref
    }
}

// ---------------- per-cluster ctx partials: 8 chunk-blocks/cluster, 512 thr, 8-row interleave ----------------
__global__ __launch_bounds__(512)
void k_ctx(const float* __restrict__ h, const float* __restrict__ e,
           const int* __restrict__ order, const int* __restrict__ cnt,
           float* __restrict__ ctxPart, float* __restrict__ denPart){
    int b = blockIdx.x;              // 0..7999
    int c = b >> 3, q = b & 7;
    int n_all = min(cnt[c*PAD], CAP);
    int c0 = (n_all * q) >> 3, c1 = (n_all * (q+1)) >> 3;
    int n = c1 - c0;
    int start = c*CAP + c0;
    int t = threadIdx.x;
    __shared__ int idxL[512];
    __shared__ float eL[512];
    __shared__ float redL[8][256];
    __shared__ float dsum[8];
    int r8 = t >> 6;                 // wave id 0..7: rows == r8 mod 8
    int col4 = (t & 63) << 2;        // float4 column
    float ax = 0.f, ay = 0.f, az = 0.f, aw = 0.f;
    float dpart = 0.f;
    for (int base = 0; base < n; base += 512){
        int m = min(512, n - base);
        if (t < m){
            int nd = order[start + base + t];
            idxL[t] = nd;
            float ev = e[nd];
            eL[t] = ev;
            dpart += ev;
        }
        __syncthreads();
        #pragma unroll 8
        for (int i = r8; i < m; i += 8){
            float ev = eL[i];
            float4 hv = *reinterpret_cast<const float4*>(h + (size_t)idxL[i]*Dd + col4);
            ax = fmaf(ev, hv.x, ax);
            ay = fmaf(ev, hv.y, ay);
            az = fmaf(ev, hv.z, az);
            aw = fmaf(ev, hv.w, aw);
        }
        __syncthreads();
    }
    *reinterpret_cast<float4*>(&redL[r8][col4]) = (float4){ax, ay, az, aw};
    #pragma unroll
    for (int off = 1; off < 64; off <<= 1) dpart += __shfl_xor(dpart, off);
    if ((t & 63) == 0) dsum[r8] = dpart;
    __syncthreads();
    if (t < 256){
        float s = ((redL[0][t] + redL[1][t]) + (redL[2][t] + redL[3][t]))
                + ((redL[4][t] + redL[5][t]) + (redL[6][t] + redL[7][t]));
        ctxPart[((size_t)c*8 + q)*Dd + t] = s;
    }
    if (t == 0)
        denPart[b] = ((dsum[0]+dsum[1])+(dsum[2]+dsum[3]))+((dsum[4]+dsum[5])+(dsum[6]+dsum[7]));
}

// ---------------- virtual-node side: 1 cluster/block, 512 thr, 2-way k-split ----------------
__global__ __launch_bounds__(512)
void k_vn(const float* __restrict__ ctxPart, const float* __restrict__ denPart,
          const float* __restrict__ g_hat,
          const float* __restrict__ Wv, const float* __restrict__ bv,
          const float* __restrict__ H2w, const float* __restrict__ H2b,
          const float* __restrict__ G2w, const float* __restrict__ G2b,
          float* __restrict__ out){
    int c = blockIdx.x, t = threadIdx.x;
    int d = t & 255, half = t >> 8;
    __shared__ float cL[Dd], gtL[Dd], ghL[Dd];
    __shared__ float red[2][Dd];
    if (half == 0){
        float den = 0.f, num = 0.f;
        #pragma unroll
        for (int q = 0; q < 8; ++q){
            den += denPart[c*8 + q];
            num += ctxPart[((size_t)c*8 + q)*Dd + d];
        }
        float inv = (den > 0.f) ? 1.f/den : 0.f;   // empty cluster -> ctx = 0 (matches ref)
        cL[d]  = num * inv;
        ghL[d] = g_hat[(size_t)c*Dd + d];
    }
    __syncthreads();
    int k0 = half*128;
    float a1 = 0.f;
    #pragma unroll 4
    for (int k2 = 0; k2 < 128; ++k2){
        int k = k0 + k2;
        a1 = fmaf(cL[k], Wv[k*Dd + d], a1);
    }
    red[half][d] = a1;
    __syncthreads();
    if (half == 0)
        gtL[d] = tanhf(red[0][d] + red[1][d] + bv[d]);
    __syncthreads();
    float a2 = 0.f;
    #pragma unroll 4
    for (int k2 = 0; k2 < 128; ++k2){
        int k = k0 + k2;
        a2 = fmaf(gtL[k], H2w[k*Dd + d], a2);
        a2 = fmaf(ghL[k], G2w[k*Dd + d], a2);
    }
    red[half][d] = a2;
    __syncthreads();
    if (half == 0){
        float a2v = red[0][d] + red[1][d] + H2b[d] + G2b[d];
        float z = 1.f / (1.f + expf(-a2v));
        out[(size_t)(Nn + c)*Dd + d] = (1.f - z)*gtL[d] + z*ghL[d];
    }
}

extern "C" void kernel_launch(void* const* d_in, const int* in_sizes, int n_in,
                              void* d_out, int out_size, void* d_ws, size_t ws_size,
                              hipStream_t stream){
    const float* h       = (const float*)d_in[0];
    const float* g       = (const float*)d_in[1];
    const float* g_hat   = (const float*)d_in[2];
    const int*   seg     = (const int*)  d_in[3];
    const float* Wq      = (const float*)d_in[4];
    const float* Wk      = (const float*)d_in[5];
    const float* b_attn  = (const float*)d_in[6];
    const float* w_score = (const float*)d_in[7];
    const float* b_score = (const float*)d_in[8];
    const float* Wv      = (const float*)d_in[9];
    const float* bv      = (const float*)d_in[10];
    const float* Ws      = (const float*)d_in[11];
    const float* bs      = (const float*)d_in[12];
    const float* H1w     = (const float*)d_in[13];
    const float* H1b     = (const float*)d_in[14];
    const float* G1w     = (const float*)d_in[15];
    const float* G1b     = (const float*)d_in[16];
    const float* H2w     = (const float*)d_in[17];
    const float* H2b     = (const float*)d_in[18];
    const float* G2w     = (const float*)d_in[19];
    const float* G2b     = (const float*)d_in[20];
    float* out = (float*)d_out;

    char* ws = (char*)d_ws;
    unsigned short* wfragK = (unsigned short*)(ws + 0);      //   131,072 B  (ct 0..7)
    unsigned short* wfragH = (unsigned short*)(ws + 131072); //   131,072 B  (ct 8..15, contiguous)
    float* qb          = (float*)(ws +  262144);             // 1,024,000 B
    unsigned int* ctht = (unsigned int*)(ws + 1286144);      // 1,024,000 B (packed cterm|h_trans)
    float* e       = (float*)(ws + 2310144);                 //   800,000 B
    int*   order   = (int*)  (ws + 3110144);                 // 2,048,000 B (CAP-bucketed)
    int*   cnt     = (int*)  (ws + 5158144);                 //    64,000 B (padded x16)
    float* ctxPart = (float*)(ws + 5222144);                 // 8,192,000 B (8 partials/cluster)
    float* denPart = (float*)(ws + 13414144);                //    32,000 B

    hipLaunchKernelGGL(k_prep, dim3(64), dim3(256), 0, stream, Wk, H1w, wfragK, wfragH, cnt);
    hipLaunchKernelGGL(k_cluster_prep, dim3(Cc), dim3(512), 0, stream,
                       g, Wq, b_attn, Ws, bs, G1w, G1b, H1b, qb, ctht);
    hipLaunchKernelGGL(k_scatter, dim3((Nn + 255)/256), dim3(256), 0, stream, seg, cnt, order);
    hipLaunchKernelGGL(k_gemm9, dim3(NCH8), dim3(512), 0, stream,
                       h, wfragK, seg, qb, w_score, b_score, ctht, e, out);
    hipLaunchKernelGGL(k_ctx, dim3(Cc*8), dim3(512), 0, stream, h, e, order, cnt, ctxPart, denPart);
    hipLaunchKernelGGL(k_vn, dim3(Cc), dim3(512), 0, stream,
                       ctxPart, denPart, g_hat, Wv, bv, H2w, H2b, G2w, G2b, out);
}

// Round 19
// 297.805 us; speedup vs baseline: 1.5986x; 1.5986x over previous
//
#include <hip/hip_runtime.h>
#include <hip/hip_bf16.h>

#define Nn 200000
#define Cc 1000
#define Dd 256
#define PAD 16        // counter padding (one per 64B line)
#define NCH8 3125     // Nn / 64 chunks, one per block
#define CAP 512       // per-cluster order capacity (mean 200, sigma 14 -> +22 sigma)

typedef float f32x16 __attribute__((ext_vector_type(16)));
typedef short bf16x8 __attribute__((ext_vector_type(8)));
typedef _Float16 f16x2 __attribute__((ext_vector_type(2)));

#define LOG2E  1.4426950408889634f
#define LOG2E2 2.8853900817779268f

__device__ __forceinline__ unsigned int f2bf(float x){
    union { float f; unsigned int u; } c; c.f = x;
    unsigned int u = c.u;
    u += 0x7fffu + ((u >> 16) & 1u);   // round-to-nearest-even
    return u >> 16;
}
__device__ __forceinline__ float bf2f(unsigned short b){
    union { unsigned int u; float f; } c; c.u = ((unsigned int)b) << 16;
    return c.f;
}
__device__ __forceinline__ float rcp_(float x){ return __builtin_amdgcn_rcpf(x); }

// ---------------- prep: W fragment tables (MFMA 32x32x16 operand order) + zero cnt ----------------
__global__ void k_prep(const float* __restrict__ Wk, const float* __restrict__ H1w,
                       unsigned short* __restrict__ wfragK, unsigned short* __restrict__ wfragH,
                       int* __restrict__ cnt){
    int t = blockIdx.x*256 + threadIdx.x;       // 64 x 256 = 16384
    if (t < Cc*PAD) cnt[t] = 0;
    int arr = t >> 13;
    int s   = t & 8191;
    int ct  = s >> 10;
    int kk  = (s >> 6) & 15;
    int l   = s & 63;
    int col = ct*32 + (l & 31);
    int k0  = kk*16 + (l >> 5)*8;
    const float* W = arr ? H1w : Wk;
    unsigned short* dst = (arr ? wfragH : wfragK) + (size_t)s*8;
    #pragma unroll
    for (int e = 0; e < 8; ++e) dst[e] = (unsigned short)f2bf(W[(size_t)(k0+e)*Dd + col]);
}

// ---------------- per-cluster precompute: 1 cluster/block, 512 thr, 2-way k-split ----------------
// outputs: qb (fp32) and ctht (packed: hi16 = bf16(cterm), lo16 = bf16(h_trans))
__global__ __launch_bounds__(512)
void k_cluster_prep(const float* __restrict__ g, const float* __restrict__ Wq,
                    const float* __restrict__ b_attn,
                    const float* __restrict__ Ws, const float* __restrict__ bs,
                    const float* __restrict__ G1w, const float* __restrict__ G1b,
                    const float* __restrict__ H1b,
                    float* __restrict__ qb, unsigned int* __restrict__ ctht){
    int c = blockIdx.x, t = threadIdx.x;
    int d = t & 255, half = t >> 8;
    __shared__ float gL[Dd], htL[Dd];
    __shared__ float redA[2][Dd], redS[2][Dd];
    if (half == 0) gL[d] = g[(size_t)c*Dd + d];
    __syncthreads();
    int k0 = half*128;
    float aq = 0.f, as = 0.f;
    #pragma unroll 4
    for (int k2 = 0; k2 < 128; ++k2){
        int k = k0 + k2;
        float gv = gL[k];
        aq = fmaf(gv, Wq[k*Dd + d], aq);
        as = fmaf(gv, Ws[k*Dd + d], as);
    }
    redA[half][d] = aq;
    redS[half][d] = as;
    __syncthreads();
    if (half == 0){
        qb[(size_t)c*Dd + d] = redA[0][d] + redA[1][d] + b_attn[d];
        htL[d] = tanhf(redS[0][d] + redS[1][d] + bs[d]);
    }
    __syncthreads();
    float ac = 0.f;
    #pragma unroll 4
    for (int k2 = 0; k2 < 128; ++k2){
        int k = k0 + k2;
        ac = fmaf(htL[k], G1w[k*Dd + d], ac);
    }
    redA[half][d] = ac;
    __syncthreads();
    if (half == 0){
        float acv = redA[0][d] + redA[1][d] + H1b[d] + G1b[d];
        ctht[(size_t)c*Dd + d] = (f2bf(acv) << 16) | f2bf(htL[d]);
    }
}

// ---------------- capacity-bucket scatter (no scan needed; order within cluster irrelevant) ----------------
__global__ void k_scatter(const int* __restrict__ seg, int* __restrict__ cnt, int* __restrict__ order){
    int i = blockIdx.x*256 + threadIdx.x;
    if (i < Nn){
        int c = seg[i];
        int p = atomicAdd(&cnt[c*PAD], 1);
        if (p < CAP) order[c*CAP + p] = i;
    }
}

// ================= fused score+merge GEMM: R14 structure + packed-f16 score reduction =================
// (R17 configuration — validated optimum: 2 accumulators/wave, 16 waves, compiler-scheduled W loads,
//  packed-f16 pairwise shuffle reduction. R18's 4-acc variant spilled; R12/R11 pipelining failed.)
__global__ __launch_bounds__(1024, 4)
void k_gemm8(const float* __restrict__ h, const unsigned short* __restrict__ wfrag,
             const int* __restrict__ seg, const float* __restrict__ qb,
             const float* __restrict__ w_score, const float* __restrict__ b_score,
             const unsigned int* __restrict__ ctht,
             float* __restrict__ e, float* __restrict__ out){
    __shared__ __align__(16) char Al[32768];    // 64 nodes x 512B bf16, XOR-swizzled
    __shared__ float sPart[64][8];
    __shared__ int segL[64];

    int tid = threadIdx.x;
    int w = tid >> 6, l = tid & 63;             // w = 0..15
    int lCol = l & 31, hiK = l >> 5;
    int rowBase = blockIdx.x * 64;

    {
        const float4* hv = reinterpret_cast<const float4*>(h + (size_t)rowBase * Dd);
        float4 v[4];
        #pragma unroll
        for (int j = 0; j < 4; ++j) v[j] = hv[j*1024 + tid];
        if (tid < 64) segL[tid] = seg[rowBase + tid];
        #pragma unroll
        for (int j = 0; j < 4; ++j){
            int f = j*1024 + tid;
            int row = f >> 6;
            unsigned long long pk = (unsigned long long)f2bf(v[j].x)
                                  | ((unsigned long long)f2bf(v[j].y) << 16)
                                  | ((unsigned long long)f2bf(v[j].z) << 32)
                                  | ((unsigned long long)f2bf(v[j].w) << 48);
            int byte = (row*512 + (f & 63)*8) ^ ((row & 15) << 4);
            *reinterpret_cast<unsigned long long*>(Al + byte) = pk;
        }
    }
    __syncthreads();   // A ready

    int hOff = lCol*512;
    int swzK = (lCol & 15) << 4;
    const char* wb = reinterpret_cast<const char*>(wfrag) + (size_t)w*16384 + l*16;

    f32x16 acc0, acc1;
    #pragma unroll
    for (int i = 0; i < 16; ++i){ acc0[i] = 0.f; acc1[i] = 0.f; }
    #pragma unroll
    for (int kk = 0; kk < 16; ++kk){
        bf16x8 wF = *reinterpret_cast<const bf16x8*>(wb + (size_t)kk*1024);
        int hb = (hOff + kk*32 + hiK*16) ^ swzK;
        bf16x8 hF0 = *reinterpret_cast<const bf16x8*>(Al + hb);
        bf16x8 hF1 = *reinterpret_cast<const bf16x8*>(Al + 16384 + hb);
        acc0 = __builtin_amdgcn_mfma_f32_32x32x16_bf16(hF0, wF, acc0, 0, 0, 0);
        acc1 = __builtin_amdgcn_mfma_f32_32x32x16_bf16(hF1, wF, acc1, 0, 0, 0);
    }

    if (w < 8){
        // score: v = tanh(y + qb[seg]) * w_score; pairwise-packed f16 reduction over 32 cols.
        float wsc = w_score[w*32 + lCol];
        #pragma unroll
        for (int nt = 0; nt < 2; ++nt){
            const f32x16& A = nt ? acc1 : acc0;
            #pragma unroll
            for (int p = 0; p < 8; ++p){
                int i0 = 2*p, i1 = 2*p + 1;
                int n0 = nt*32 + (i0&3) + 8*(i0>>2) + 4*hiK;
                int n1 = nt*32 + (i1&3) + 8*(i1>>2) + 4*hiK;
                float q0 = qb[(size_t)segL[n0]*Dd + w*32 + lCol];
                float q1 = qb[(size_t)segL[n1]*Dd + w*32 + lCol];
                float t0 = exp2f(LOG2E2*(A[i0] + q0));
                float t1 = exp2f(LOG2E2*(A[i1] + q1));
                float v0 = (t0 - 1.f)*rcp_(t0 + 1.f)*wsc;
                float v1 = (t1 - 1.f)*rcp_(t1 + 1.f)*wsc;
                f16x2 pk; pk.x = (_Float16)v0; pk.y = (_Float16)v1;
                #pragma unroll
                for (int off = 1; off <= 16; off <<= 1){
                    union { f16x2 f; int i; } cv, co;
                    cv.f = pk;
                    co.i = __shfl_xor(cv.i, off);
                    pk = pk + co.f;              // v_pk_add_f16: both rows per op
                }
                if (lCol == 0){
                    sPart[n0][w] = (float)pk.x;
                    sPart[n1][w] = (float)pk.y;
                }
            }
        }
    } else {
        int cb = (w - 8)*32 + lCol;
        #pragma unroll
        for (int nt = 0; nt < 2; ++nt){
            const f32x16& A = nt ? acc1 : acc0;
            #pragma unroll
            for (int i = 0; i < 16; ++i){
                int node = nt*32 + (i&3) + 8*(i>>2) + 4*hiK;
                unsigned int v = ctht[(size_t)segL[node]*Dd + cb];
                float c4 = bf2f((unsigned short)(v >> 16));
                float t4 = bf2f((unsigned short)(v & 0xffff));
                unsigned short hb = *reinterpret_cast<const unsigned short*>(
                    Al + ((node*512 + cb*2) ^ ((node & 15) << 4)));
                float hval = bf2f(hb);
                float z = rcp_(1.f + exp2f(-LOG2E*(A[i] + c4)));
                out[(size_t)(rowBase + node)*Dd + cb] = fmaf(z, t4 - hval, hval);
            }
        }
    }

    __syncthreads();   // sPart complete
    if (tid < 64){
        float s = sPart[tid][0] + sPart[tid][1] + sPart[tid][2] + sPart[tid][3]
                + sPart[tid][4] + sPart[tid][5] + sPart[tid][6] + sPart[tid][7] + b_score[0];
        e[rowBase + tid] = exp2f(LOG2E * s);   // unshifted exp: |s| small, ratio == ref
    }
}

// ---------------- per-cluster ctx partials: 8 chunk-blocks/cluster, 512 thr, 8-row interleave ----------------
__global__ __launch_bounds__(512)
void k_ctx(const float* __restrict__ h, const float* __restrict__ e,
           const int* __restrict__ order, const int* __restrict__ cnt,
           float* __restrict__ ctxPart, float* __restrict__ denPart){
    int b = blockIdx.x;              // 0..7999
    int c = b >> 3, q = b & 7;
    int n_all = min(cnt[c*PAD], CAP);
    int c0 = (n_all * q) >> 3, c1 = (n_all * (q+1)) >> 3;
    int n = c1 - c0;
    int start = c*CAP + c0;
    int t = threadIdx.x;
    __shared__ int idxL[512];
    __shared__ float eL[512];
    __shared__ float redL[8][256];
    __shared__ float dsum[8];
    int r8 = t >> 6;                 // wave id 0..7: rows == r8 mod 8
    int col4 = (t & 63) << 2;        // float4 column
    float ax = 0.f, ay = 0.f, az = 0.f, aw = 0.f;
    float dpart = 0.f;
    for (int base = 0; base < n; base += 512){
        int m = min(512, n - base);
        if (t < m){
            int nd = order[start + base + t];
            idxL[t] = nd;
            float ev = e[nd];
            eL[t] = ev;
            dpart += ev;
        }
        __syncthreads();
        #pragma unroll 8
        for (int i = r8; i < m; i += 8){
            float ev = eL[i];
            float4 hv = *reinterpret_cast<const float4*>(h + (size_t)idxL[i]*Dd + col4);
            ax = fmaf(ev, hv.x, ax);
            ay = fmaf(ev, hv.y, ay);
            az = fmaf(ev, hv.z, az);
            aw = fmaf(ev, hv.w, aw);
        }
        __syncthreads();
    }
    *reinterpret_cast<float4*>(&redL[r8][col4]) = (float4){ax, ay, az, aw};
    #pragma unroll
    for (int off = 1; off < 64; off <<= 1) dpart += __shfl_xor(dpart, off);
    if ((t & 63) == 0) dsum[r8] = dpart;
    __syncthreads();
    if (t < 256){
        float s = ((redL[0][t] + redL[1][t]) + (redL[2][t] + redL[3][t]))
                + ((redL[4][t] + redL[5][t]) + (redL[6][t] + redL[7][t]));
        ctxPart[((size_t)c*8 + q)*Dd + t] = s;
    }
    if (t == 0)
        denPart[b] = ((dsum[0]+dsum[1])+(dsum[2]+dsum[3]))+((dsum[4]+dsum[5])+(dsum[6]+dsum[7]));
}

// ---------------- virtual-node side: 1 cluster/block, 512 thr, 2-way k-split ----------------
__global__ __launch_bounds__(512)
void k_vn(const float* __restrict__ ctxPart, const float* __restrict__ denPart,
          const float* __restrict__ g_hat,
          const float* __restrict__ Wv, const float* __restrict__ bv,
          const float* __restrict__ H2w, const float* __restrict__ H2b,
          const float* __restrict__ G2w, const float* __restrict__ G2b,
          float* __restrict__ out){
    int c = blockIdx.x, t = threadIdx.x;
    int d = t & 255, half = t >> 8;
    __shared__ float cL[Dd], gtL[Dd], ghL[Dd];
    __shared__ float red[2][Dd];
    if (half == 0){
        float den = 0.f, num = 0.f;
        #pragma unroll
        for (int q = 0; q < 8; ++q){
            den += denPart[c*8 + q];
            num += ctxPart[((size_t)c*8 + q)*Dd + d];
        }
        float inv = (den > 0.f) ? 1.f/den : 0.f;   // empty cluster -> ctx = 0 (matches ref)
        cL[d]  = num * inv;
        ghL[d] = g_hat[(size_t)c*Dd + d];
    }
    __syncthreads();
    int k0 = half*128;
    float a1 = 0.f;
    #pragma unroll 4
    for (int k2 = 0; k2 < 128; ++k2){
        int k = k0 + k2;
        a1 = fmaf(cL[k], Wv[k*Dd + d], a1);
    }
    red[half][d] = a1;
    __syncthreads();
    if (half == 0)
        gtL[d] = tanhf(red[0][d] + red[1][d] + bv[d]);
    __syncthreads();
    float a2 = 0.f;
    #pragma unroll 4
    for (int k2 = 0; k2 < 128; ++k2){
        int k = k0 + k2;
        a2 = fmaf(gtL[k], H2w[k*Dd + d], a2);
        a2 = fmaf(ghL[k], G2w[k*Dd + d], a2);
    }
    red[half][d] = a2;
    __syncthreads();
    if (half == 0){
        float a2v = red[0][d] + red[1][d] + H2b[d] + G2b[d];
        float z = 1.f / (1.f + expf(-a2v));
        out[(size_t)(Nn + c)*Dd + d] = (1.f - z)*gtL[d] + z*ghL[d];
    }
}

extern "C" void kernel_launch(void* const* d_in, const int* in_sizes, int n_in,
                              void* d_out, int out_size, void* d_ws, size_t ws_size,
                              hipStream_t stream){
    const float* h       = (const float*)d_in[0];
    const float* g       = (const float*)d_in[1];
    const float* g_hat   = (const float*)d_in[2];
    const int*   seg     = (const int*)  d_in[3];
    const float* Wq      = (const float*)d_in[4];
    const float* Wk      = (const float*)d_in[5];
    const float* b_attn  = (const float*)d_in[6];
    const float* w_score = (const float*)d_in[7];
    const float* b_score = (const float*)d_in[8];
    const float* Wv      = (const float*)d_in[9];
    const float* bv      = (const float*)d_in[10];
    const float* Ws      = (const float*)d_in[11];
    const float* bs      = (const float*)d_in[12];
    const float* H1w     = (const float*)d_in[13];
    const float* H1b     = (const float*)d_in[14];
    const float* G1w     = (const float*)d_in[15];
    const float* G1b     = (const float*)d_in[16];
    const float* H2w     = (const float*)d_in[17];
    const float* H2b     = (const float*)d_in[18];
    const float* G2w     = (const float*)d_in[19];
    const float* G2b     = (const float*)d_in[20];
    float* out = (float*)d_out;

    char* ws = (char*)d_ws;
    unsigned short* wfragK = (unsigned short*)(ws + 0);      //   131,072 B  (ct 0..7)
    unsigned short* wfragH = (unsigned short*)(ws + 131072); //   131,072 B  (ct 8..15, contiguous)
    float* qb          = (float*)(ws +  262144);             // 1,024,000 B
    unsigned int* ctht = (unsigned int*)(ws + 1286144);      // 1,024,000 B (packed cterm|h_trans)
    float* e       = (float*)(ws + 2310144);                 //   800,000 B
    int*   order   = (int*)  (ws + 3110144);                 // 2,048,000 B (CAP-bucketed)
    int*   cnt     = (int*)  (ws + 5158144);                 //    64,000 B (padded x16)
    float* ctxPart = (float*)(ws + 5222144);                 // 8,192,000 B (8 partials/cluster)
    float* denPart = (float*)(ws + 13414144);                //    32,000 B

    hipLaunchKernelGGL(k_prep, dim3(64), dim3(256), 0, stream, Wk, H1w, wfragK, wfragH, cnt);
    hipLaunchKernelGGL(k_cluster_prep, dim3(Cc), dim3(512), 0, stream,
                       g, Wq, b_attn, Ws, bs, G1w, G1b, H1b, qb, ctht);
    hipLaunchKernelGGL(k_scatter, dim3((Nn + 255)/256), dim3(256), 0, stream, seg, cnt, order);
    hipLaunchKernelGGL(k_gemm8, dim3(NCH8), dim3(1024), 0, stream,
                       h, wfragK, seg, qb, w_score, b_score, ctht, e, out);
    hipLaunchKernelGGL(k_ctx, dim3(Cc*8), dim3(512), 0, stream, h, e, order, cnt, ctxPart, denPart);
    hipLaunchKernelGGL(k_vn, dim3(Cc), dim3(512), 0, stream,
                       ctxPart, denPart, g_hat, Wv, bv, H2w, H2b, G2w, G2b, out);
}